// Round 1
// 180.724 us; speedup vs baseline: 1.0701x; 1.0701x over previous
//
#include <hip/hip_runtime.h>
#include <stdint.h>

typedef __attribute__((ext_vector_type(8))) short bf16x8;
typedef __attribute__((ext_vector_type(4))) float f32x4;

#define HH  100   // history length
#define DD  128   // embedding dim d
#define HID 256   // hidden width / concat dim

__device__ __forceinline__ unsigned short f2bf(float f) {
    unsigned int u = __float_as_uint(f);
    u += 0x7fffu + ((u >> 16) & 1u);   // round-to-nearest-even
    return (unsigned short)(u >> 16);
}

// Pack W1 (256x256 f32, [n][k]) into MFMA B-fragment order, bf16 (RNE — runs once).
// unit = (st*8+s)*64 + lane holds W1[st*16 + (lane&15)][s*32 + (lane>>4)*8 + j], j=0..7
__global__ void w1_pack(const float* __restrict__ W1, unsigned short* __restrict__ W1p) {
    int unit = blockIdx.x * 256 + threadIdx.x;   // 0..8191
    int lane = unit & 63;
    int s    = (unit >> 6) & 7;
    int st   = unit >> 9;
    int col  = lane & 15, quad = lane >> 4;
    const float* src = W1 + (size_t)(st * 16 + col) * HID + s * 32 + quad * 8;
    union { unsigned short u[8]; bf16x8 v; } o;
    #pragma unroll
    for (int j = 0; j < 8; j++) o.u[j] = f2bf(src[j]);
    *(bf16x8*)(W1p + (size_t)unit * 8) = o.v;
}

// Flipped decomposition: B (W1p) is register-resident per wave (wave w owns st strips
// {2w, 2w+1} = 16 bf16x8 frags = 64 VGPR, loaded once from L2-hot W1p). A (gathered X)
// goes through LDS once: wave w gathers m-tile w (16 rows) and stores A-fragments to
// LDS as they are built (no afrag array -> gather and MFMA phases don't overlap in
// registers). m-tile 7 (rows 112..127, all padding) is skipped entirely.
// Barriers: 4 total, no global_load_lds, no per-stage vmcnt(0) drains.
__global__ __launch_bounds__(512, 4) void nais_kernel(
    const int* __restrict__ history,           // [B,HH]
    const int* __restrict__ target,            // [B]
    const int* __restrict__ history_region,    // [B,HH]
    const int* __restrict__ target_region,     // [B]
    const float* __restrict__ target_distance, // [B]
    const float* __restrict__ E_hist,          // [item,128]
    const float* __restrict__ E_tgt,           // [item,128]
    const float* __restrict__ E_reg,           // [region,128]
    const float* __restrict__ E_dist,          // [16,128]
    const float* __restrict__ b1,              // [256]
    const float* __restrict__ w2,              // [256]
    const unsigned short* __restrict__ W1p,    // packed bf16 B-fragments (128 KB)
    float* __restrict__ out)                   // [B]
{
    // A-fragments: 7 m-tiles x 8 s x 64 lanes x 8 bf16 = 56 KB
    __shared__ __align__(16) unsigned short As[7 * 4096];
    __shared__ __align__(16) float scorep[8][112];   // per-wave 32-col score partials
    __shared__ __align__(16) float tgts[HID];
    __shared__ __align__(16) float b1s[HID];
    __shared__ __align__(16) float w2s[HID];
    __shared__ float xsum[112];
    __shared__ float eA[HH];
    __shared__ float exs[HH];
    __shared__ int hidx[HH];
    __shared__ int hreg[HH];
    __shared__ float s_sumE;

    const int b    = blockIdx.x;
    const int t    = threadIdx.x;
    const int lane = t & 63;
    const int wave = t >> 6;                   // 0..7
    const int col  = lane & 15;
    const int quad = lane >> 4;

    const int   tg    = target[b];
    const float tdist = target_distance[b];

    // ---- phase 0: stage indices, tgt vector, b1/w2, sum(E_dist[0]) ----
    if (t < HH) {
        hidx[t] = history[b * HH + t];
        hreg[t] = history_region[b * HH + t];
    }
    if (wave == 4) {
        float4 v;
        if (lane < 32) v = *(const float4*)(E_tgt + (size_t)tg * DD + lane * 4);
        else           v = *(const float4*)(E_reg + (size_t)target_region[b] * DD + (lane - 32) * 4);
        *(float4*)(tgts + lane * 4) = v;
    }
    if (wave == 5) {
        *(float4*)(b1s + lane * 4) = *(const float4*)(b1 + lane * 4);
        *(float4*)(w2s + lane * 4) = *(const float4*)(w2 + lane * 4);
    }
    if (wave == 6) {
        float v = E_dist[lane] + E_dist[64 + lane];
        #pragma unroll
        for (int off = 32; off; off >>= 1) v += __shfl_xor(v, off);
        if (lane == 0) s_sumE = v;
    }
    __syncthreads();

    // ---- phase 1: gather E-rows, build A-frags straight into LDS, xsum ----
    // rows 100..111 (tail of m-tile 6) clamp to row-64: L2-hot re-reads, never read
    // downstream. A-frag element: lane(col,quad), k = s*32 + quad*8 + j.
    if (wave < 7) {
        const int row = wave * 16 + col;
        const int rc  = (row < HH) ? row : row - 64;
        const int ih  = hidx[rc];
        const int ir  = hreg[rc];
        const float* ph = E_hist + (size_t)ih * DD + quad * 8;
        const float* pr = E_reg  + (size_t)ir * DD + quad * 8;
        unsigned short* ap = As + (size_t)wave * 4096;
        float acc = 0.f;
        #pragma unroll
        for (int c = 0; c < 2; c++) {            // chunk: 8 float4 in flight (spill guard)
            #pragma unroll
            for (int si = 0; si < 4; si++) {
                const int s = c * 4 + si;
                const float* src = (s < 4) ? (ph + s * 32) : (pr + (s - 4) * 32);
                float4 v0 = *(const float4*)src;
                float4 v1 = *(const float4*)(src + 4);
                const float* tp = tgts + s * 32 + quad * 8;
                float4 t0 = *(const float4*)tp, t1 = *(const float4*)(tp + 4);
                float x0 = v0.x * t0.x, x1 = v0.y * t0.y, x2 = v0.z * t0.z, x3 = v0.w * t0.w;
                float x4 = v1.x * t1.x, x5 = v1.y * t1.y, x6 = v1.z * t1.z, x7 = v1.w * t1.w;
                acc += (x0 + x1) + (x2 + x3) + ((x4 + x5) + (x6 + x7));
                union { unsigned short u[8]; bf16x8 v; } fb;
                fb.u[0] = f2bf(x0); fb.u[1] = f2bf(x1); fb.u[2] = f2bf(x2); fb.u[3] = f2bf(x3);
                fb.u[4] = f2bf(x4); fb.u[5] = f2bf(x5); fb.u[6] = f2bf(x6); fb.u[7] = f2bf(x7);
                *(bf16x8*)(ap + (size_t)(s * 64 + lane) * 8) = fb.v;   // contiguous, conflict-free
            }
            asm volatile("" ::: "memory");
        }
        float v = acc;
        v += __shfl_xor(v, 16);
        v += __shfl_xor(v, 32);
        if (quad == 0) xsum[row] = v;            // rows >= HH written, never read
    }

    // ---- B fragments -> registers (issued before the barrier; waited at/after it) ----
    // wave w needs units ((2w+sti)*8+s)*64+lane, 256 B/lane, coalesced, L2-hot.
    bf16x8 bfrag[16];
    #pragma unroll
    for (int i = 0; i < 16; i++) {
        const int unit = ((2 * wave + (i >> 3)) * 8 + (i & 7)) * 64 + lane;
        bfrag[i] = *(const bf16x8*)(W1p + (size_t)unit * 8);
    }
    __syncthreads();

    // ---- phase 2: score partials via MFMA; wave sweeps 7 m-tiles x its 2 st strips ----
    const int st0 = 2 * wave;
    const float bb0 = b1s[st0 * 16 + col],      ww0 = w2s[st0 * 16 + col];
    const float bb1 = b1s[st0 * 16 + 16 + col], ww1 = w2s[st0 * 16 + 16 + col];
    #pragma unroll 1
    for (int i = 0; i < 7; i++) {
        int mt = wave + i; if (mt >= 7) mt -= 7;         // stagger start to spread LDS reads
        const unsigned short* ap = As + (size_t)mt * 4096;
        f32x4 a0 = {0.f, 0.f, 0.f, 0.f}, a1 = {0.f, 0.f, 0.f, 0.f};
        #pragma unroll
        for (int s = 0; s < 8; s++) {
            bf16x8 af = *(const bf16x8*)(ap + (size_t)(s * 64 + lane) * 8);
            a0 = __builtin_amdgcn_mfma_f32_16x16x32_bf16(af, bfrag[s],     a0, 0, 0, 0);
            a1 = __builtin_amdgcn_mfma_f32_16x16x32_bf16(af, bfrag[8 + s], a1, 0, 0, 0);
        }
        // relu + w2, reduce over this wave's 16 cols per strip, stash partials
        f32x4 sv;
        #pragma unroll
        for (int r = 0; r < 4; r++) {
            float z0 = a0[r] + bb0;
            float z1 = a1[r] + bb1;
            float sres = ((z0 > 0.f) ? z0 * ww0 : 0.f) + ((z1 > 0.f) ? z1 * ww1 : 0.f);
            sres += __shfl_xor(sres, 1);
            sres += __shfl_xor(sres, 2);
            sres += __shfl_xor(sres, 4);
            sres += __shfl_xor(sres, 8);
            sv[r] = sres;
        }
        if (col == 0) *(f32x4*)&scorep[wave][mt * 16 + quad * 4] = sv;
    }
    __syncthreads();

    // ---- phase 3: cross-wave score reduce, masked exp, denom^BETA, sigmoid ----
    float sc = 0.f;
    if (t < 112) {
        #pragma unroll
        for (int w = 0; w < 8; w++) sc += scorep[w][t];
    }
    const float dist = tdist * s_sumE;
    if (t < HH) {
        float e = (hidx[t] != tg) ? expf(sc + dist) : 0.f;
        eA[t]  = e;
        exs[t] = e * xsum[t];
    }
    __syncthreads();
    if (t < 64) {
        float s1 = eA[t]  + ((t + 64 < HH) ? eA[t + 64]  : 0.f);
        float s2 = exs[t] + ((t + 64 < HH) ? exs[t + 64] : 0.f);
        #pragma unroll
        for (int off = 32; off; off >>= 1) {
            s1 += __shfl_xor(s1, off);
            s2 += __shfl_xor(s2, off);
        }
        if (t == 0) {
            float pred = s2 / sqrtf(s1);   // exp_sum^0.5 (BETA=0.5)
            out[b] = 1.f / (1.f + expf(-pred));
        }
    }
}

extern "C" void kernel_launch(void* const* d_in, const int* in_sizes, int n_in,
                              void* d_out, int out_size, void* d_ws, size_t ws_size,
                              hipStream_t stream) {
    const int*   history         = (const int*)d_in[0];
    const int*   target          = (const int*)d_in[1];
    const int*   history_region  = (const int*)d_in[2];
    const int*   target_region   = (const int*)d_in[3];
    const float* target_distance = (const float*)d_in[4];
    const float* E_hist          = (const float*)d_in[5];
    const float* E_tgt           = (const float*)d_in[6];
    const float* E_reg           = (const float*)d_in[7];
    const float* E_dist          = (const float*)d_in[8];
    const float* W1              = (const float*)d_in[9];
    const float* b1              = (const float*)d_in[10];
    const float* w2              = (const float*)d_in[11];

    unsigned short* W1p = (unsigned short*)d_ws;  // 131072 B
    const int B = in_sizes[1];

    w1_pack<<<32, 256, 0, stream>>>(W1, W1p);
    nais_kernel<<<B, 512, 0, stream>>>(history, target, history_region, target_region,
                                       target_distance, E_hist, E_tgt, E_reg, E_dist,
                                       b1, w2, W1p, (float*)d_out);
}

// Round 2
// 178.217 us; speedup vs baseline: 1.0852x; 1.0141x over previous
//
#include <hip/hip_runtime.h>
#include <stdint.h>

typedef __attribute__((ext_vector_type(8))) short bf16x8;
typedef __attribute__((ext_vector_type(4))) float f32x4;

#define HH  100   // history length
#define DD  128   // embedding dim d
#define HID 256   // hidden width / concat dim

__device__ __forceinline__ unsigned short f2bf(float f) {
    unsigned int u = __float_as_uint(f);
    u += 0x7fffu + ((u >> 16) & 1u);   // round-to-nearest-even
    return (unsigned short)(u >> 16);
}

// Pack W1 (256x256 f32, [n][k]) into MFMA fragment order, bf16 (RNE — runs once).
// unit = (st*8+s)*64 + lane holds W1[st*16 + (lane&15)][s*32 + (lane>>4)*8 + j], j=0..7
// NOTE: for 16x16x32 this order serves as BOTH the B-fragment (B[k][n]) and the
// A-fragment (A[n][k]) — lane&15 is the n index, quad*8+j the k index either way.
__global__ void w1_pack(const float* __restrict__ W1, unsigned short* __restrict__ W1p) {
    int unit = blockIdx.x * 256 + threadIdx.x;   // 0..8191
    int lane = unit & 63;
    int s    = (unit >> 6) & 7;
    int st   = unit >> 9;
    int col  = lane & 15, quad = lane >> 4;
    const float* src = W1 + (size_t)(st * 16 + col) * HID + s * 32 + quad * 8;
    union { unsigned short u[8]; bf16x8 v; } o;
    #pragma unroll
    for (int j = 0; j < 8; j++) o.u[j] = f2bf(src[j]);
    *(bf16x8*)(W1p + (size_t)unit * 8) = o.v;
}

// Wave w owns n-strips {2w, 2w+1} with W1 fragments PINNED in 64 VGPRs (inline-asm tie
// prevents the compiler sinking the loads into the m-tile loop — round-1 failure mode).
// Phase 2 computes Z^T = W1 · X^T (swapped operands), so D[row = n-within-strip][col = m]:
// the relu·w2 reduction over n is per-lane accumulation + 2 shfl per tile (was 16/tile).
__global__ __launch_bounds__(512, 4) void nais_kernel(
    const int* __restrict__ history,           // [B,HH]
    const int* __restrict__ target,            // [B]
    const int* __restrict__ history_region,    // [B,HH]
    const int* __restrict__ target_region,     // [B]
    const float* __restrict__ target_distance, // [B]
    const float* __restrict__ E_hist,          // [item,128]
    const float* __restrict__ E_tgt,           // [item,128]
    const float* __restrict__ E_reg,           // [region,128]
    const float* __restrict__ E_dist,          // [16,128]
    const float* __restrict__ b1,              // [256]
    const float* __restrict__ w2,              // [256]
    const unsigned short* __restrict__ W1p,    // packed bf16 fragments (128 KB)
    float* __restrict__ out)                   // [B]
{
    // X-fragments: 7 m-tiles x 8 s x 64 lanes x 8 bf16 = 56 KB
    __shared__ __align__(16) unsigned short As[7 * 4096];
    __shared__ __align__(16) float scorep[8][112];   // per-wave 32-n score partials
    __shared__ __align__(16) float tgts[HID];
    __shared__ __align__(16) float b1s[HID];
    __shared__ __align__(16) float w2s[HID];
    __shared__ float xsum[112];
    __shared__ float eA[HH];
    __shared__ float exs[HH];
    __shared__ int hidx[HH];
    __shared__ int hreg[HH];
    __shared__ float s_sumE;

    const int b    = blockIdx.x;
    const int t    = threadIdx.x;
    const int lane = t & 63;
    const int wave = t >> 6;                   // 0..7
    const int col  = lane & 15;
    const int quad = lane >> 4;

    const int   tg    = target[b];
    const float tdist = target_distance[b];

    // ---- phase 0: stage indices, tgt vector, b1/w2, sum(E_dist[0]) ----
    if (t < HH) {
        hidx[t] = history[b * HH + t];
        hreg[t] = history_region[b * HH + t];
    }
    if (wave == 4) {
        float4 v;
        if (lane < 32) v = *(const float4*)(E_tgt + (size_t)tg * DD + lane * 4);
        else           v = *(const float4*)(E_reg + (size_t)target_region[b] * DD + (lane - 32) * 4);
        *(float4*)(tgts + lane * 4) = v;
    }
    if (wave == 5) {
        *(float4*)(b1s + lane * 4) = *(const float4*)(b1 + lane * 4);
        *(float4*)(w2s + lane * 4) = *(const float4*)(w2 + lane * 4);
    }
    if (wave == 6) {
        float v = E_dist[lane] + E_dist[64 + lane];
        #pragma unroll
        for (int off = 32; off; off >>= 1) v += __shfl_xor(v, off);
        if (lane == 0) s_sumE = v;
    }
    __syncthreads();

    // ---- phase 1: gather E-rows, build X-frags straight into LDS, xsum ----
    // rows 100..111 clamp to row-64: L2-hot re-reads, never read downstream.
    // X-frag element: lane(col,quad), k = s*32 + quad*8 + j  (s<4: E_hist, s>=4: E_reg)
    if (wave < 7) {
        const int row = wave * 16 + col;
        const int rc  = (row < HH) ? row : row - 64;
        const int ih  = hidx[rc];
        const int ir  = hreg[rc];
        const float* ph = E_hist + (size_t)ih * DD + quad * 8;
        const float* pr = E_reg  + (size_t)ir * DD + quad * 8;
        unsigned short* ap = As + (size_t)wave * 4096;
        float acc = 0.f;
        #pragma unroll
        for (int s = 0; s < 8; s++) {           // all 16 float4 gathers in flight
            const float* src = (s < 4) ? (ph + s * 32) : (pr + (s - 4) * 32);
            float4 v0 = *(const float4*)src;
            float4 v1 = *(const float4*)(src + 4);
            const float* tp = tgts + s * 32 + quad * 8;
            float4 t0 = *(const float4*)tp, t1 = *(const float4*)(tp + 4);
            float x0 = v0.x * t0.x, x1 = v0.y * t0.y, x2 = v0.z * t0.z, x3 = v0.w * t0.w;
            float x4 = v1.x * t1.x, x5 = v1.y * t1.y, x6 = v1.z * t1.z, x7 = v1.w * t1.w;
            acc += (x0 + x1) + (x2 + x3) + ((x4 + x5) + (x6 + x7));
            union { unsigned short u[8]; bf16x8 v; } fb;
            fb.u[0] = f2bf(x0); fb.u[1] = f2bf(x1); fb.u[2] = f2bf(x2); fb.u[3] = f2bf(x3);
            fb.u[4] = f2bf(x4); fb.u[5] = f2bf(x5); fb.u[6] = f2bf(x6); fb.u[7] = f2bf(x7);
            *(bf16x8*)(ap + (size_t)(s * 64 + lane) * 8) = fb.v;   // contiguous, conflict-free
        }
        float v = acc;
        v += __shfl_xor(v, 16);
        v += __shfl_xor(v, 32);
        if (quad == 0) xsum[row] = v;            // rows >= HH written, never read
    }

    // ---- W1 fragments -> registers, PINNED (issued before barrier; L2-hot) ----
    bf16x8 w1f[16];
    #pragma unroll
    for (int i = 0; i < 16; i++) {
        const int unit = ((2 * wave + (i >> 3)) * 8 + (i & 7)) * 64 + lane;
        w1f[i] = *(const bf16x8*)(W1p + (size_t)unit * 8);
    }
    #pragma unroll
    for (int i = 0; i < 16; i++) asm volatile("" : "+v"(w1f[i]));  // forbid sinking/re-load
    __syncthreads();

    // ---- phase 2: Z^T tiles via MFMA; per-lane n-accumulation of relu(z)*w2 ----
    // D[row = n = st*16 + quad*4 + r][col = m = mt*16 + col]
    const int st0 = 2 * wave;
    const f32x4 bb0 = *(const f32x4*)&b1s[st0 * 16 + quad * 4];
    const f32x4 bb1 = *(const f32x4*)&b1s[st0 * 16 + 16 + quad * 4];
    const f32x4 ww0 = *(const f32x4*)&w2s[st0 * 16 + quad * 4];
    const f32x4 ww1 = *(const f32x4*)&w2s[st0 * 16 + 16 + quad * 4];
    #pragma unroll 1
    for (int i = 0; i < 7; i++) {
        int mt = wave + i; if (mt >= 7) mt -= 7;         // stagger to spread LDS reads
        const unsigned short* ap = As + (size_t)mt * 4096;
        f32x4 a0 = {0.f, 0.f, 0.f, 0.f}, a1 = {0.f, 0.f, 0.f, 0.f};
        #pragma unroll
        for (int s = 0; s < 8; s++) {
            bf16x8 xf = *(const bf16x8*)(ap + (size_t)(s * 64 + lane) * 8);
            a0 = __builtin_amdgcn_mfma_f32_16x16x32_bf16(w1f[s],     xf, a0, 0, 0, 0);
            a1 = __builtin_amdgcn_mfma_f32_16x16x32_bf16(w1f[8 + s], xf, a1, 0, 0, 0);
        }
        float sp = 0.f;
        #pragma unroll
        for (int r = 0; r < 4; r++) {
            float z0 = a0[r] + bb0[r];
            float z1 = a1[r] + bb1[r];
            sp += ((z0 > 0.f) ? z0 * ww0[r] : 0.f) + ((z1 > 0.f) ? z1 * ww1[r] : 0.f);
        }
        sp += __shfl_xor(sp, 16);                        // sum over quads: 2 steps only
        sp += __shfl_xor(sp, 32);
        if (quad == 0) scorep[wave][mt * 16 + col] = sp;
    }
    __syncthreads();

    // ---- phase 3: cross-wave score reduce, masked exp, denom^BETA, sigmoid ----
    float sc = 0.f;
    if (t < 112) {
        #pragma unroll
        for (int w = 0; w < 8; w++) sc += scorep[w][t];
    }
    const float dist = tdist * s_sumE;
    if (t < HH) {
        float e = (hidx[t] != tg) ? expf(sc + dist) : 0.f;
        eA[t]  = e;
        exs[t] = e * xsum[t];
    }
    __syncthreads();
    if (t < 64) {
        float s1 = eA[t]  + ((t + 64 < HH) ? eA[t + 64]  : 0.f);
        float s2 = exs[t] + ((t + 64 < HH) ? exs[t + 64] : 0.f);
        #pragma unroll
        for (int off = 32; off; off >>= 1) {
            s1 += __shfl_xor(s1, off);
            s2 += __shfl_xor(s2, off);
        }
        if (t == 0) {
            float pred = s2 / sqrtf(s1);   // exp_sum^0.5 (BETA=0.5)
            out[b] = 1.f / (1.f + expf(-pred));
        }
    }
}

extern "C" void kernel_launch(void* const* d_in, const int* in_sizes, int n_in,
                              void* d_out, int out_size, void* d_ws, size_t ws_size,
                              hipStream_t stream) {
    const int*   history         = (const int*)d_in[0];
    const int*   target          = (const int*)d_in[1];
    const int*   history_region  = (const int*)d_in[2];
    const int*   target_region   = (const int*)d_in[3];
    const float* target_distance = (const float*)d_in[4];
    const float* E_hist          = (const float*)d_in[5];
    const float* E_tgt           = (const float*)d_in[6];
    const float* E_reg           = (const float*)d_in[7];
    const float* E_dist          = (const float*)d_in[8];
    const float* W1              = (const float*)d_in[9];
    const float* b1              = (const float*)d_in[10];
    const float* w2              = (const float*)d_in[11];

    unsigned short* W1p = (unsigned short*)d_ws;  // 131072 B
    const int B = in_sizes[1];

    w1_pack<<<32, 256, 0, stream>>>(W1, W1p);
    nais_kernel<<<B, 512, 0, stream>>>(history, target, history_region, target_region,
                                       target_distance, E_hist, E_tgt, E_reg, E_dist,
                                       b1, w2, W1p, (float*)d_out);
}